// Round 3
// baseline (523.191 us; speedup 1.0000x reference)
//
#include <hip/hip_runtime.h>
#include <math.h>

typedef _Float16 f16;
typedef _Float16 f16x8 __attribute__((ext_vector_type(8)));
typedef float f32x4 __attribute__((ext_vector_type(4)));

#define HH 32
#define WW 64
#define NPX 2048
#define SLOTS 68          // 64 px + 2 halo each side
#define CHS 78336         // 36*68*32 f16 = one 32-ci slab of the halo grid
// lo-planes pre-scaled by 2^11 to stay in fp16 NORMAL range (denormal inputs
// are flushed by the MFMA pipe -- proven by earlier bit-identical failure)
#define LOSCALE 2048.0f
#define INV_LOSCALE 4.8828125e-4f

typedef const __attribute__((address_space(1))) void gvoid;
typedef __attribute__((address_space(3))) void lvoid;
__device__ __forceinline__ void gload_lds16(const void* g, void* l) {
    __builtin_amdgcn_global_load_lds((gvoid*)g, (lvoid*)l, 16, 0, 0);
}

// ---- zero halo act buffers (P|Q|X0 contiguous in ws; re-poisoned every call)
__global__ void zero_kernel(f16* p, int n8) {
    int i = blockIdx.x * 256 + threadIdx.x;
    if (i < n8) *(int4*)(p + i * 8) = make_int4(0, 0, 0, 0);
}

// ---- prep: X0 halo buffer [cic][row][slot][ci32], hi=(data-3.5)*mask, lo=0
__global__ void prep_kernel(const float* __restrict__ data,
                            const float* __restrict__ mask,
                            f16* __restrict__ X0, int plane) {
    int idx = blockIdx.x * 256 + threadIdx.x;      // px*64 + ci
    if (idx >= NPX * 64) return;
    int px = idx >> 6, ci = idx & 63;
    int hh = px >> 6, w = px & 63;
    float v = (data[ci * NPX + px] - 3.5f) * mask[ci * NPX + px];
    int dst = (ci >> 5) * CHS + ((hh + 2) * SLOTS + (w + 2)) * 32 + (ci & 31);
    X0[dst] = (f16)v;
    X0[plane + dst] = (f16)0.f;
}

// ---- repack to fully-tiled layout: [tap25][coT=co/16][cic=ci/32][co16][ci32]
// -> each A-fragment (16co x 32ci) is one contiguous 1KB tile (lane-coalesced).
// is_out: co_p = g*2+c -> orig co = g*3+1+c (mu,sig only; logits provably unused)
__global__ void repack_kernel(const float* __restrict__ W, f16* __restrict__ WP,
                              int cin_log2, int coutp_log2,
                              int cpg_in_log2, int limb, int is_out) {
    int idx = blockIdx.x * 256 + threadIdx.x;
    int Cin = 1 << cin_log2;
    int plane = 25 << (cin_log2 + coutp_log2);
    int ci = idx & (Cin - 1);
    int rest = idx >> cin_log2;
    int co_p = rest & ((1 << coutp_log2) - 1);
    int tap = rest >> coutp_log2;
    if (tap >= 25) return;
    int ky = tap / 5, kx = tap - 5 * ky;
    int co_orig, g_out;
    if (is_out) { g_out = co_p >> 1; co_orig = 3 * g_out + 1 + (co_p & 1); }
    else        { g_out = co_p >> 2; co_orig = co_p; }
    int g_in = ci >> cpg_in_log2;
    float v = 0.f;
    if (ky + kx <= limb + g_out - g_in)
        v = W[(co_orig * Cin + ci) * 25 + tap];
    f16 vh = (f16)v;
    int dst = (((tap << (coutp_log2 - 4)) + (co_p >> 4)) << (cin_log2 - 5 + 9))
            + ((ci >> 5) << 9) + ((co_p & 15) << 5) + (ci & 31);
    WP[dst] = vh;
    WP[plane + dst] = (f16)((v - (float)vh) * LOSCALE);
}

// ---- fused conv V4: implicit GEMM, split-fp16, ky-per-wave.
// Two complementary 16-co tiles (mt1=big drives the K loop, mt0=small rides
// along) share every staged B chunk and every B ds_read -> LDS-read and
// staging bytes per FLOP halve vs V3, and per-block chunk counts are
// near-balanced (pair maxes 8,8,8,7,7,6,6,5).
// grid = 8 pairs x 32 h = 256 blocks (1/CU); blockIdx%8 = pair -> each XCD's
// 32 blocks share one 820KB weight pair (L2-resident, was L3).
// Pipeline per chunk: [16 unconditional A-frag preloads (oldest)]
// [s_waitcnt vmcnt(16): retires exactly the previous stage, wave-uniform]
// [s_barrier] [kx loop: B ds_reads+MFMAs; stage(next) issues at kx==1 so its
// L2 latency hides under ~3 kx of MFMAs; kx4-A prefetch at kx==2] [s_barrier].
// No vmcnt(0) in the main loop. Double-buffered LDS 2x44KB.
__global__ __launch_bounds__(320, 2) void conv_kernel(
    const f16* __restrict__ IN, int Cin, int inPlane,
    const f16* __restrict__ WP, int wPlane,
    const float* __restrict__ bias,
    const f16* __restrict__ RES, int resPlane,
    f16* __restrict__ OA, int oaPlane,
    float* __restrict__ OT,
    int nmt, int Coutp, int cpg_out, int cpg_in, int limb, int mode, int paired)
{
    __shared__ __align__(16) char SMEM[92160];   // 2 x 46080 (43520B data + pad)
    f16* BL = (f16*)SMEM;
    float* RED = (float*)SMEM;  // [kw5][px64][col pad36] f32 = 46080 B after loop

    const int t = threadIdx.x;
    const int kw = t >> 6;                 // wave index == ky
    const int lane = t & 63, l15 = lane & 15, q = lane >> 4;

    const int nhalf = paired ? (nmt >> 1) : nmt;   // 8 in all launches
    const int mtp = blockIdx.x % nhalf;
    const int h = blockIdx.x / nhalf;
    const int mt1 = paired ? (nmt - 1 - mtp) : mtp;   // primary (bigger K range)
    const int mt0 = paired ? mtp : -1;                // secondary (may be absent)

    const int g1 = (mt1 * 16 + 15) / cpg_out;
    const int g0 = mt0 >= 0 ? (mt0 * 16 + 15) / cpg_out : 0;

    // masked K-extent per kx (allowed iff ky+kx <= limb + g_out - g_in)
    int cnt1[5], cnt0[5];
#pragma unroll
    for (int kx = 0; kx < 5; kx++) {
        int c = (g1 + limb - kw - kx + 1) * cpg_in;
        c = c < Cin ? c : Cin;
        cnt1[kx] = c > 0 ? c : 0;
        if (mt0 >= 0) {
            int d = (g0 + limb - kw - kx + 1) * cpg_in;
            d = d < Cin ? d : Cin;
            cnt0[kx] = d > 0 ? d : 0;
        } else cnt0[kx] = 0;
    }
    int ci_top = (g1 + limb + 1) * cpg_in;
    ci_top = ci_top < Cin ? ci_top : Cin;
    const int NT = (ci_top + 31) >> 5;

    // per-lane staging source offsets (f16 units), linear [pl][row5][slot68][ci32]
    int soff[9];
#pragma unroll
    for (int r = 0; r < 9; r++) {
        int u = r * 320 + t;
        if (u >= 2720) u = 0;              // tail lanes: any valid addr (dest=pad)
        int pl = u >= 1360 ? 1 : 0;
        int rem = u - pl * 1360;
        soff[r] = pl * inPlane + h * 2176 + rem * 8;
    }

    f32x4 a1h[4], a1m[4], a0h[4], a0m[4];
#pragma unroll
    for (int j = 0; j < 4; j++) {
        a1h[j] = (f32x4){0.f, 0.f, 0.f, 0.f};
        a1m[j] = (f32x4){0.f, 0.f, 0.f, 0.f};
        a0h[j] = (f32x4){0.f, 0.f, 0.f, 0.f};
        a0m[j] = (f32x4){0.f, 0.f, 0.f, 0.f};
    }

    // tiled weights: tile (tap, coT, cic) is 512 f16 contiguous
    const size_t kxs = (size_t)Coutp * Cin;            // per-kx tap stride
    const size_t tileStride = (size_t)Cin << 4;
    const f16* w1b = WP + (size_t)(kw * 5 * (Coutp >> 4) + mt1) * tileStride
                   + l15 * 32 + q * 8;
    const f16* w0b = WP + (size_t)(kw * 5 * (Coutp >> 4) + (mt0 >= 0 ? mt0 : 0)) * tileStride
                   + l15 * 32 + q * 8;

    // prologue: stage chunk 0 -> buf 0 (9 rounds x 5 waves, waves 3,4 do 8)
#pragma unroll
    for (int r = 0; r < 9; r++) {
        int ub = r * 320 + kw * 64;
        if (ub < 2720) gload_lds16(IN + soff[r], BL + ub * 8);
    }

    for (int it = 0; it < NT; ++it) {
        const int ci0 = it << 5;
        f16* buf = BL + (it & 1) * 23040;
        const f16* w1 = w1b + it * 512;
        const f16* w0 = w0b + it * 512;

        // 16 unconditional A preloads (masked weights are exact zeros in WP,
        // so out-of-range frags are valid memory; bodies are guarded anyway).
        // These are the 16 NEWEST vmem ops -> vmcnt(16) retires prev stage.
        f16x8 A1h[5], A1l[5], A0h[5], A0l[5];
#pragma unroll
        for (int kx = 0; kx < 4; kx++) {
            A1h[kx] = *(const f16x8*)(w1 + kx * kxs);
            A1l[kx] = *(const f16x8*)(w1 + kx * kxs + wPlane);
            A0h[kx] = *(const f16x8*)(w0 + kx * kxs);
            A0l[kx] = *(const f16x8*)(w0 + kx * kxs + wPlane);
        }
        asm volatile("s_waitcnt vmcnt(16)" ::: "memory");
        __builtin_amdgcn_s_barrier();
        asm volatile("" ::: "memory");

        const f16* bhp = buf + kw * 2176 + q * 8;          // [slot68][ci32] rows
        const f16* blp = buf + 10880 + kw * 2176 + q * 8;  // lo plane (+5 rows)

#pragma unroll
        for (int kx = 0; kx < 5; kx++) {
            if (kx == 1 && it + 1 < NT) {
                // stage next chunk into the other buffer; its latency hides
                // under kx=1..4 MFMAs; retired by next iteration's vmcnt(16)
                f16* nb = BL + ((it & 1) ^ 1) * 23040;
                const int coff = (it + 1) * CHS;
#pragma unroll
                for (int r = 0; r < 9; r++) {
                    int ub = r * 320 + kw * 64;
                    if (ub < 2720) gload_lds16(IN + soff[r] + coff, nb + ub * 8);
                }
            }
            if (kx == 2) {                 // late A prefetch for kx=4
                if (ci0 < cnt1[4]) {
                    A1h[4] = *(const f16x8*)(w1 + 4 * kxs);
                    A1l[4] = *(const f16x8*)(w1 + 4 * kxs + wPlane);
                }
                if (ci0 < cnt0[4]) {
                    A0h[4] = *(const f16x8*)(w0 + 4 * kxs);
                    A0l[4] = *(const f16x8*)(w0 + 4 * kxs + wPlane);
                }
            }
            if (ci0 < cnt1[kx]) {          // wave-uniform in practice
                f16x8 bh[4], bl[4];
#pragma unroll
                for (int j = 0; j < 4; j++) {
                    int slt = j * 16 + l15 + kx;
                    bh[j] = *(const f16x8*)(bhp + slt * 32);
                    bl[j] = *(const f16x8*)(blp + slt * 32);
                }
#pragma unroll
                for (int j = 0; j < 4; j++) {
                    a1h[j] = __builtin_amdgcn_mfma_f32_16x16x32_f16(A1h[kx], bh[j], a1h[j], 0, 0, 0);
                    a1m[j] = __builtin_amdgcn_mfma_f32_16x16x32_f16(A1h[kx], bl[j], a1m[j], 0, 0, 0);
                    a1m[j] = __builtin_amdgcn_mfma_f32_16x16x32_f16(A1l[kx], bh[j], a1m[j], 0, 0, 0);
                }
                if (ci0 < cnt0[kx]) {
#pragma unroll
                    for (int j = 0; j < 4; j++) {
                        a0h[j] = __builtin_amdgcn_mfma_f32_16x16x32_f16(A0h[kx], bh[j], a0h[j], 0, 0, 0);
                        a0m[j] = __builtin_amdgcn_mfma_f32_16x16x32_f16(A0h[kx], bl[j], a0m[j], 0, 0, 0);
                        a0m[j] = __builtin_amdgcn_mfma_f32_16x16x32_f16(A0l[kx], bh[j], a0m[j], 0, 0, 0);
                    }
                }
            }
        }
        __builtin_amdgcn_s_barrier();      // all reads of buf done before overwrite
        asm volatile("" ::: "memory");
    }

    // in-block ky reduction through LDS (C/D: px=j*16+l15, co=q*4+r)
    // tile1 -> cols 0..15, tile0 -> cols 16..31
#pragma unroll
    for (int j = 0; j < 4; j++) {
        f32x4 v;
#pragma unroll
        for (int r = 0; r < 4; r++)
            v[r] = a1h[j][r] + a1m[j][r] * INV_LOSCALE;
        *(f32x4*)&RED[(kw * 64 + j * 16 + l15) * 36 + q * 4] = v;
        if (mt0 >= 0) {
            f32x4 u;
#pragma unroll
            for (int r = 0; r < 4; r++)
                u[r] = a0h[j][r] + a0m[j][r] * INV_LOSCALE;
            *(f32x4*)&RED[(kw * 64 + j * 16 + l15) * 36 + 16 + q * 4] = u;
        }
    }
    __syncthreads();

    if (mode == 0) {
        // bias + relu (+ residual) -> split-f16 halo store (chunk-major layout)
        const int tot = mt0 >= 0 ? 2048 : 1024;
        for (int c = t; c < tot; c += 320) {
            int px, col;
            if (mt0 >= 0) { px = c >> 5; col = c & 31; }
            else          { px = c >> 4; col = c & 15; }
            int co = col < 16 ? mt1 * 16 + col : mt0 * 16 + (col - 16);
            float v = bias[co];
#pragma unroll
            for (int k5 = 0; k5 < 5; k5++) v += RED[(k5 * 64 + px) * 36 + col];
            v = fmaxf(v, 0.f);
            int o = (co >> 5) * CHS + ((h + 2) * SLOTS + px + 2) * 32 + (co & 31);
            if (RES) v += (float)RES[o] + (float)RES[resPlane + o] * INV_LOSCALE;
            f16 vh = (f16)v;
            OA[o] = vh;
            OA[oaPlane + o] = (f16)((v - (float)vh) * LOSCALE);
        }
    } else {
        // output conv (unpaired): co_p = g*2+{mu,sig}; bias+softplus+erf fused
        for (int c = t; c < 1024; c += 320) {
            int px = c >> 4, col = c & 15;
            float v = bias[3 * ((mt1 * 16 + col) >> 1) + 1 + (col & 1)];
#pragma unroll
            for (int k5 = 0; k5 < 5; k5++) v += RED[(k5 * 64 + px) * 36 + col];
            RED[px * 36 + col] = v;    // own-cell write after own-cell reads: safe
        }
        __syncthreads();
        for (int c = t; c < 512; c += 320) {
            int px = c >> 3, gl = c & 7;
            float mu = RED[px * 36 + 2 * gl];
            float s  = RED[px * 36 + 2 * gl + 1];
            float sp = fmaxf(s, 0.f) + log1pf(expf(-fabsf(s)));
            float sig = sp + 1e-6f;
            float inv = 1.f / (sig * 1.41421356237f);
            int g = (mt1 * 16 >> 1) + gl;
            float* o = OT + ((size_t)g * NPX + h * WW + px) * 8;
#pragma unroll
            for (int k = 0; k < 8; k++) {
                float z = ((float)k - 3.0f - mu) * inv;
                o[k] = 32768.f * (1.f + erff(z));
            }
        }
    }
}

extern "C" void kernel_launch(void* const* d_in, const int* in_sizes, int n_in,
                              void* d_out, int out_size, void* d_ws, size_t ws_size,
                              hipStream_t stream) {
    const float* data  = (const float*)d_in[0];
    const float* mask  = (const float*)d_in[1];
    const float* w_in  = (const float*)d_in[2];
    const float* b_in  = (const float*)d_in[3];
    const float* w_hid = (const float*)d_in[4];
    const float* b_hid = (const float*)d_in[5];
    const float* w_out = (const float*)d_in[6];
    const float* b_out = (const float*)d_in[7];
    float* out = (float*)d_out;

    // ws: WP 6.55MB | P 2.51 | Q 2.51 | X0 0.63  = 12.2 MB total
    f16* WP = (f16*)d_ws;                  // 2 x 25*256*256 f16
    f16* P  = WP + 3276800;                // 2 x 8*CHS f16 (halo act, x)
    f16* Q  = P + 1253376;                 // 2 x 8*CHS f16 (halo act, h1)
    f16* X0 = Q + 1253376;                 // 2 x 2*CHS f16

    // zero P|Q|X0 (contiguous): 2,820,096 f16 = 352,512 x (8 f16)
    zero_kernel<<<1377, 256, 0, stream>>>(P, 352512);
    prep_kernel<<<512, 256, 0, stream>>>(data, mask, X0, 156672);

    // input conv: Cin=64, strict (limb=3), cpg_in=1 -> P (paired)
    repack_kernel<<<1600, 256, 0, stream>>>(w_in, WP, 6, 8, 0, 3, 0);
    conv_kernel<<<256, 320, 0, stream>>>(X0, 64, 156672, WP, 409600,
        b_in, nullptr, 0, P, 626688, nullptr, 16, 256, 4, 1, 3, 0, 1);

    for (int i = 0; i < 5; i++) {
        repack_kernel<<<6400, 256, 0, stream>>>(w_hid + (size_t)(2 * i) * 1638400,
                                                WP, 8, 8, 2, 4, 0);
        conv_kernel<<<256, 320, 0, stream>>>(P, 256, 626688, WP, 1638400,
            b_hid + 2 * i * 256, nullptr, 0, Q, 626688, nullptr, 16, 256, 4, 4, 4, 0, 1);
        repack_kernel<<<6400, 256, 0, stream>>>(w_hid + (size_t)(2 * i + 1) * 1638400,
                                                WP, 8, 8, 2, 4, 0);
        // conv2: residual x (P) added after relu, written back in-place to P
        conv_kernel<<<256, 320, 0, stream>>>(Q, 256, 626688, WP, 1638400,
            b_hid + (2 * i + 1) * 256, P, 626688, P, 626688, nullptr, 16, 256, 4, 4, 4, 0, 1);
    }

    // output conv: mu/sig only (Coutp=128, cpg_out=2, limb=4) + fused erf table
    repack_kernel<<<3200, 256, 0, stream>>>(w_out, WP, 8, 7, 2, 4, 1);
    conv_kernel<<<256, 320, 0, stream>>>(P, 256, 626688, WP, 819200,
        b_out, nullptr, 0, nullptr, 0, out, 8, 128, 2, 4, 4, 1, 0);
}

// Round 4
// 448.673 us; speedup vs baseline: 1.1661x; 1.1661x over previous
//
#include <hip/hip_runtime.h>
#include <math.h>

typedef _Float16 f16;
typedef _Float16 f16x8 __attribute__((ext_vector_type(8)));
typedef float f32x4 __attribute__((ext_vector_type(4)));

#define HH 32
#define WW 64
#define NPX 2048
#define SLOTS 68          // 64 px + 2 halo each side
#define CHS 78336         // 36*68*32 f16 = one 32-ci slab of the halo grid
// lo-planes pre-scaled by 2^11 to stay in fp16 NORMAL range (denormal inputs
// are flushed by the MFMA pipe -- proven by earlier bit-identical failure)
#define LOSCALE 2048.0f
#define INV_LOSCALE 4.8828125e-4f

typedef const __attribute__((address_space(1))) void gvoid;
typedef __attribute__((address_space(3))) void lvoid;
__device__ __forceinline__ void gload_lds16(const void* g, void* l) {
    __builtin_amdgcn_global_load_lds((gvoid*)g, (lvoid*)l, 16, 0, 0);
}

// ---- zero halo act buffers (P|Q|X0 contiguous in ws; re-poisoned every call)
__global__ void zero_kernel(f16* p, int n8) {
    int i = blockIdx.x * 256 + threadIdx.x;
    if (i < n8) *(int4*)(p + i * 8) = make_int4(0, 0, 0, 0);
}

// ---- prep: X0 halo buffer [cic][row][slot][ci32], hi=(data-3.5)*mask, lo=0
__global__ void prep_kernel(const float* __restrict__ data,
                            const float* __restrict__ mask,
                            f16* __restrict__ X0, int plane) {
    int idx = blockIdx.x * 256 + threadIdx.x;      // px*64 + ci
    if (idx >= NPX * 64) return;
    int px = idx >> 6, ci = idx & 63;
    int hh = px >> 6, w = px & 63;
    float v = (data[ci * NPX + px] - 3.5f) * mask[ci * NPX + px];
    int dst = (ci >> 5) * CHS + ((hh + 2) * SLOTS + (w + 2)) * 32 + (ci & 31);
    X0[dst] = (f16)v;
    X0[plane + dst] = (f16)0.f;
}

// ---- repack to fully-tiled layout: [tap25][coT=co/16][cic=ci/32][co16][ci32]
// -> each A-fragment (16co x 32ci) is one contiguous 1KB tile (lane-coalesced).
// is_out: co_p = g*2+c -> orig co = g*3+1+c (mu,sig only; logits provably unused)
__global__ void repack_kernel(const float* __restrict__ W, f16* __restrict__ WP,
                              int cin_log2, int coutp_log2,
                              int cpg_in_log2, int limb, int is_out) {
    int idx = blockIdx.x * 256 + threadIdx.x;
    int Cin = 1 << cin_log2;
    int plane = 25 << (cin_log2 + coutp_log2);
    int ci = idx & (Cin - 1);
    int rest = idx >> cin_log2;
    int co_p = rest & ((1 << coutp_log2) - 1);
    int tap = rest >> coutp_log2;
    if (tap >= 25) return;
    int ky = tap / 5, kx = tap - 5 * ky;
    int co_orig, g_out;
    if (is_out) { g_out = co_p >> 1; co_orig = 3 * g_out + 1 + (co_p & 1); }
    else        { g_out = co_p >> 2; co_orig = co_p; }
    int g_in = ci >> cpg_in_log2;
    float v = 0.f;
    if (ky + kx <= limb + g_out - g_in)
        v = W[(co_orig * Cin + ci) * 25 + tap];
    f16 vh = (f16)v;
    int dst = (((tap << (coutp_log2 - 4)) + (co_p >> 4)) << (cin_log2 - 5 + 9))
            + ((ci >> 5) << 9) + ((co_p & 15) << 5) + (ci & 31);
    WP[dst] = vh;
    WP[plane + dst] = (f16)((v - (float)vh) * LOSCALE);
}

// ---- fused conv V5 = V3 structure + XCD-affinity swizzle + kx0-A hoist.
// V3 proven structure: 16co x 64px per wave (1x4 frags of mfma_f32_16x16x32_f16),
// ky-per-wave (5 waves), single-buffered LDS stage via global_load_lds,
// 2 blocks/CU, complementary (mt, nmt-1-mt) pairing for balanced K-work.
// NEW (1): block decode puts pairIdx = blockIdx&7 -> HW round-robin lands all
// blocks of one mt-pair on ONE XCD; weight tiles touched per XCD per conv drop
// ~4MB -> ~475KB (L2-resident; +act 2.5MB < 4MB L2). Previously A-frag loads
// missed L2 every kx (depth-1 prefetch ~190cy << L3 ~500cy) = dominant stall.
// NEW (2): chunk's kx=0 A-frags load BEFORE the staging barrier, so their
// latency drains with the stage instead of serially after it.
__global__ __launch_bounds__(320, 3) void conv_kernel(
    const f16* __restrict__ IN, int Cin, int inPlane,
    const f16* __restrict__ WP, int wPlane,
    const float* __restrict__ bias,
    const f16* __restrict__ RES, int resPlane,
    f16* __restrict__ OA, int oaPlane,
    float* __restrict__ OT,
    int nmt, int Coutp, int cpg_out, int cpg_in, int limb, int mode)
{
    __shared__ __align__(16) char SMEM[46080];
    f16* BL = (f16*)SMEM;      // [plane2][row5][slot68][ci32] = 43520 B (+pad)
    float* RED = (float*)SMEM; // [kw5][px64][co pad20] = 25600 B (after K loop)

    const int t = threadIdx.x;
    const int kw = t >> 6;                 // wave index == ky
    const int lane = t & 63, l15 = lane & 15, q = lane >> 4;

    // XCD-affinity decode: pairIdx rides the low 3 bits (HW XCD round-robin).
    // nmt=16 (512 blocks): pair=p3(8), h=r&31, slot=r>>5; b and b+256 share
    //   p3 & h, flip slot -> complementary mt on the same CU (round-robin).
    // nmt=8 (256 blocks): pair=p3&3(4), slot=p3>>2, h=r.
    const int b = blockIdx.x;
    const int p3 = b & 7, r = b >> 3;
    int pairIdx, slot, h_;
    if (nmt == 16) { pairIdx = p3;     h_ = r & 31; slot = r >> 5; }
    else           { pairIdx = p3 & 3; h_ = r;      slot = p3 >> 2; }
    const int h = h_;
    const int mt = slot ? (nmt - 1 - pairIdx) : pairIdx;
    const int co0 = mt * 16;
    const int g_max = (co0 + 15) / cpg_out;

    // masked K-extent per kx for this wave's ky (allowed iff ky+kx<=limb+g_out-g_in)
    int cnt[5];
#pragma unroll
    for (int kx = 0; kx < 5; kx++) {
        int c = (g_max + limb - (kw + kx) + 1) * cpg_in;
        c = c < Cin ? c : Cin;
        cnt[kx] = c > 0 ? c : 0;
    }
    int ci_top = (g_max + limb + 1) * cpg_in;   // block-uniform chunk bound
    ci_top = ci_top < Cin ? ci_top : Cin;

    // per-lane staging sources: 2720 16B-units, linear in [pl][row5][slot68][ci32]
    // -> global addresses are CONSECUTIVE across lanes (contiguous 21.8KB/plane)
    const f16* src[9];
#pragma unroll
    for (int rr = 0; rr < 9; rr++) {
        int u = rr * 320 + t;
        if (u >= 2720) u = 0;              // tail lanes: any valid addr (dest=pad)
        int pl = u >= 1360 ? 1 : 0;
        int rem = u - pl * 1360;
        src[rr] = IN + (size_t)pl * inPlane + h * 2176 + rem * 8;
    }

    f32x4 acc_h[4], acc_m[4];
#pragma unroll
    for (int j = 0; j < 4; j++) {
        acc_h[j] = (f32x4){0.f, 0.f, 0.f, 0.f};
        acc_m[j] = (f32x4){0.f, 0.f, 0.f, 0.f};
    }

    // tiled weight addressing: tile (tap, mt, cic) is 512 f16 contiguous
    const size_t kxs = (size_t)Coutp * Cin;            // per-kx tap stride
    const f16* wb0 = WP + (size_t)(kw * 5 * (Coutp >> 4) + mt) * ((size_t)Cin << 4)
                   + l15 * 32 + q * 8;

    int coff = 0;                                      // (ci0/32)*CHS
    for (int ci0 = 0; ci0 < ci_top; ci0 += 32, coff += CHS) {
        __syncthreads();
        // stage B: 43520 B = 9 rounds x 5 waves x 1024 B, direct global->LDS
#pragma unroll
        for (int rr = 0; rr < 9; rr++) {
            int ub = rr * 320 + kw * 64;
            if (ub < 2720)                 // wave-uniform (BL padded for overshoot)
                gload_lds16(src[rr] + coff, BL + ub * 8);
        }
        // kx=0 A-frags issued BEFORE the barrier: latency overlaps stage drain
        const f16* wb = wb0 + (ci0 >> 5) * 512;
        f16x8 cah, cal, nah, nal;
        if (ci0 < cnt[0]) {
            cah = *(const f16x8*)(wb);
            cal = *(const f16x8*)(wb + wPlane);
        }
        __syncthreads();

#pragma unroll
        for (int kx = 0; kx < 5; kx++) {
            if (ci0 >= cnt[kx]) break;     // cnt non-increasing in kx, wave-uniform
            if (kx < 4 && ci0 < cnt[kx + 1]) {
                nah = *(const f16x8*)(wb + (kx + 1) * kxs);
                nal = *(const f16x8*)(wb + (kx + 1) * kxs + wPlane);
            }
            f16x8 bh[4], bl[4];
#pragma unroll
            for (int j = 0; j < 4; j++) {
                int slt = j * 16 + l15 + kx;
                bh[j] = *(const f16x8*)&BL[(0 * 5 + kw) * (SLOTS * 32) + slt * 32 + q * 8];
                bl[j] = *(const f16x8*)&BL[(1 * 5 + kw) * (SLOTS * 32) + slt * 32 + q * 8];
            }
#pragma unroll
            for (int j = 0; j < 4; j++) {
                acc_h[j] = __builtin_amdgcn_mfma_f32_16x16x32_f16(cah, bh[j], acc_h[j], 0, 0, 0);
                acc_m[j] = __builtin_amdgcn_mfma_f32_16x16x32_f16(cah, bl[j], acc_m[j], 0, 0, 0);
                acc_m[j] = __builtin_amdgcn_mfma_f32_16x16x32_f16(cal, bh[j], acc_m[j], 0, 0, 0);
            }
            cah = nah; cal = nal;
        }
    }

    // in-block ky reduction through LDS (C/D layout: px=j*16+l15, co=q*4+r)
    __syncthreads();   // all BL reads done before RED aliases SMEM
#pragma unroll
    for (int j = 0; j < 4; j++) {
        f32x4 v;
#pragma unroll
        for (int rr = 0; rr < 4; rr++)
            v[rr] = acc_h[j][rr] + acc_m[j][rr] * INV_LOSCALE;
        *(f32x4*)&RED[(kw * 64 + j * 16 + l15) * 20 + q * 4] = v;
    }
    __syncthreads();

    if (mode == 0) {
        // bias + relu (+ residual) -> split-f16 halo store (chunk-major layout)
        for (int c = t; c < 1024; c += 320) {
            int px = c >> 4, col = c & 15;
            float v = bias[co0 + col];
#pragma unroll
            for (int k5 = 0; k5 < 5; k5++) v += RED[(k5 * 64 + px) * 20 + col];
            v = fmaxf(v, 0.f);
            int cc = co0 + col;
            int o = (cc >> 5) * CHS + ((h + 2) * SLOTS + px + 2) * 32 + (cc & 31);
            if (RES) v += (float)RES[o] + (float)RES[resPlane + o] * INV_LOSCALE;
            f16 vh = (f16)v;
            OA[o] = vh;
            OA[oaPlane + o] = (f16)((v - (float)vh) * LOSCALE);
        }
    } else {
        // output conv: co_p = g*2 + {mu,sig}; fold bias+softplus+erf table here
        for (int c = t; c < 1024; c += 320) {
            int px = c >> 4, col = c & 15;
            float v = bias[3 * ((co0 + col) >> 1) + 1 + (col & 1)];
#pragma unroll
            for (int k5 = 0; k5 < 5; k5++) v += RED[(k5 * 64 + px) * 20 + col];
            RED[px * 20 + col] = v;    // own-cell write after own-cell reads: safe
        }
        __syncthreads();
        for (int c = t; c < 512; c += 320) {
            int px = c >> 3, gl = c & 7;
            float mu = RED[px * 20 + 2 * gl];
            float s  = RED[px * 20 + 2 * gl + 1];
            float sp = fmaxf(s, 0.f) + log1pf(expf(-fabsf(s)));
            float sig = sp + 1e-6f;
            float inv = 1.f / (sig * 1.41421356237f);
            int g = (co0 >> 1) + gl;
            float* o = OT + ((size_t)g * NPX + h * WW + px) * 8;
#pragma unroll
            for (int k = 0; k < 8; k++) {
                float z = ((float)k - 3.0f - mu) * inv;
                o[k] = 32768.f * (1.f + erff(z));
            }
        }
    }
}

extern "C" void kernel_launch(void* const* d_in, const int* in_sizes, int n_in,
                              void* d_out, int out_size, void* d_ws, size_t ws_size,
                              hipStream_t stream) {
    const float* data  = (const float*)d_in[0];
    const float* mask  = (const float*)d_in[1];
    const float* w_in  = (const float*)d_in[2];
    const float* b_in  = (const float*)d_in[3];
    const float* w_hid = (const float*)d_in[4];
    const float* b_hid = (const float*)d_in[5];
    const float* w_out = (const float*)d_in[6];
    const float* b_out = (const float*)d_in[7];
    float* out = (float*)d_out;

    // ws: WP 6.55MB | P 2.51 | Q 2.51 | X0 0.63  = 12.2 MB total
    f16* WP = (f16*)d_ws;                  // 2 x 25*256*256 f16
    f16* P  = WP + 3276800;                // 2 x 8*CHS f16 (halo act, x)
    f16* Q  = P + 1253376;                 // 2 x 8*CHS f16 (halo act, h1)
    f16* X0 = Q + 1253376;                 // 2 x 2*CHS f16

    // zero P|Q|X0 (contiguous): 2,820,096 f16 = 352,512 x (8 f16)
    zero_kernel<<<1377, 256, 0, stream>>>(P, 352512);
    prep_kernel<<<512, 256, 0, stream>>>(data, mask, X0, 156672);

    // input conv: Cin=64, strict (limb=3), cpg_in=1 -> P
    repack_kernel<<<1600, 256, 0, stream>>>(w_in, WP, 6, 8, 0, 3, 0);
    conv_kernel<<<512, 320, 0, stream>>>(X0, 64, 156672, WP, 409600,
        b_in, nullptr, 0, P, 626688, nullptr, 16, 256, 4, 1, 3, 0);

    for (int i = 0; i < 5; i++) {
        repack_kernel<<<6400, 256, 0, stream>>>(w_hid + (size_t)(2 * i) * 1638400,
                                                WP, 8, 8, 2, 4, 0);
        conv_kernel<<<512, 320, 0, stream>>>(P, 256, 626688, WP, 1638400,
            b_hid + 2 * i * 256, nullptr, 0, Q, 626688, nullptr, 16, 256, 4, 4, 4, 0);
        repack_kernel<<<6400, 256, 0, stream>>>(w_hid + (size_t)(2 * i + 1) * 1638400,
                                                WP, 8, 8, 2, 4, 0);
        // conv2: residual x (P) added after relu, written back in-place to P
        conv_kernel<<<512, 320, 0, stream>>>(Q, 256, 626688, WP, 1638400,
            b_hid + (2 * i + 1) * 256, P, 626688, P, 626688, nullptr, 16, 256, 4, 4, 4, 0);
    }

    // output conv: mu/sig only (Coutp=128, cpg_out=2, limb=4) + fused erf table
    repack_kernel<<<3200, 256, 0, stream>>>(w_out, WP, 8, 7, 2, 4, 1);
    conv_kernel<<<256, 320, 0, stream>>>(P, 256, 626688, WP, 819200,
        b_out, nullptr, 0, nullptr, 0, out, 8, 128, 2, 4, 4, 1);
}